// Round 8
// baseline (340.701 us; speedup 1.0000x reference)
//
#include <hip/hip_runtime.h>
#include <hip/hip_fp16.h>

// EdgeNetwork: SINGLE persistent kernel (prep -> barrier -> MFMA+pk-atomic
// scatter -> barrier -> finalize). Dispatch gaps (~8us each) were co-dominant
// with kernel time; 3 kernels -> 1.
//
// Journal:
// R0: hipLaunchCooperativeKernel silently no-ops under graph capture. NEVER.
// R1: occupancy x2 -> neutral. Not latency-bound.
// R3: dst-sort cut touches 3x but +3 dispatches (~8-10us each) -> net loss.
// R4: launch_bounds(256,4) -> VGPR 80->64 scratch spills. Keep (256,3).
// R5: pk_add_f16 halved atomic DWORDS, time unchanged -> wall = atomic
//     SECTOR-TOUCHES at the coherence point (~14.5G touches/s).
// R6: full-row waves, 1 pk-instr per edge-row: 800k->400k touches, edge 55-><42us.
//     Harness re-poisons the FULL 256MB ws every iteration (43us, fixed).
// R7: __hip_atomic_fence does NOT exist in this ROCm's headers -- use
//     __builtin_amdgcn_fence(order, "agent") instead. (Only compile failure.)
// R8 (this): R7 resubmitted with the builtin fence. Device-barrier notes:
//   - Residency proof: launch_bounds(256,3) caps VGPR at 170 -> >=3 blk/CU;
//     LDS 21.8KB -> 7/CU; grid=768 = 3x256 fully co-resident. No deadlock.
//   - Barrier flags live in poisoned ws -> per-block MAGIC store (poison
//     resets them each iter); spin reads use fetch_add(0) RMWs (always
//     execute at the coherence point -> immune to stale non-coherent L1/L2).
//   - Phase C MUST read accum with agent-scope atomic loads: phase-B atomics
//     RMW at the fabric and do NOT invalidate the clean L2 lines left by
//     phase-A zeroing; a plain load would return stale zeros.
//   - Bond f16 pre-conversion dropped (38.4MB pass to save 12.8MB -> stream
//     f32, convert at the splat; identical rounding). Atom conversion kept.

typedef _Float16 half8 __attribute__((ext_vector_type(8)));
typedef _Float16 half4t __attribute__((ext_vector_type(4)));
typedef float float4v __attribute__((ext_vector_type(4)));

constexpr int NA = 100000;
constexpr int E  = 400000;
constexpr int GRP   = E / 16;          // 25000 16-edge groups
constexpr int NBLK  = 768;             // exactly co-resident (see proof above)
constexpr int NWAVE = NBLK * 4;        // 3072 persistent waves
constexpr int NTHR  = NBLK * 256;      // 196608 threads

// ---- workspace layout (bytes) ----
constexpr size_t OFF_ATOMH = 0;                    // f16[NA*32]  6.4 MB
constexpr size_t OFF_ACC   = (size_t)NA * 32 * 2;  // f16[NA*32]  6.4 MB
constexpr size_t OFF_BARA  = OFF_ACC + (size_t)NA * 32 * 2;   // u32[768]
constexpr size_t OFF_BARB  = OFF_BARA + 4096;                 // u32[768]

constexpr unsigned MAGIC_A = 0x9E3779B1u;   // not byte-replicated (poison-safe)
constexpr unsigned MAGIC_B = 0x85EBCA77u;

constexpr int NZ4 = NA * 32 / 4;       // accum zero, half4t units (800k)
constexpr int NA4 = NA * 32 / 4;       // atom convert, float4 units (800k)
constexpr int PHASEA_TOT = NZ4 + NA4;  // 1.6M

constexpr int WSTRIDE = 80;            // LDS bytes per W n-row

static __device__ inline half8 splat8(_Float16 v) {
  half8 r = {v, v, v, v, v, v, v, v};
  return r;
}

// Device-wide barrier over exactly-resident NBLK blocks.
static __device__ inline void grid_barrier(unsigned* flags, unsigned magic) {
  __threadfence();            // release: waitcnt + wb L2 (covers stores+atomics)
  __syncthreads();
  if (threadIdx.x == 0) {
    (void)__hip_atomic_exchange(flags + blockIdx.x, magic, __ATOMIC_RELEASE,
                                __HIP_MEMORY_SCOPE_AGENT);
  }
  __shared__ int s_done;
  for (;;) {
    int ok = 1;
    #pragma unroll
    for (int r = 0; r < 3; ++r) {               // 3*256 = 768 flags
      const int i = threadIdx.x + r * 256;
      unsigned v = __hip_atomic_fetch_add(flags + i, 0u, __ATOMIC_RELAXED,
                                          __HIP_MEMORY_SCOPE_AGENT);
      ok &= (v == magic);
    }
    if (threadIdx.x == 0) s_done = 1;
    __syncthreads();
    if (!ok) s_done = 0;
    __syncthreads();
    if (s_done) break;
    __builtin_amdgcn_s_sleep(8);
  }
  __builtin_amdgcn_fence(__ATOMIC_ACQUIRE, "agent");
}

__global__ __launch_bounds__(256, 3)
void edge_all(const float* __restrict__ atom,
              const float* __restrict__ bondf,
              const int* __restrict__ pairs,
              const float* __restrict__ Kmat,
              const float* __restrict__ bias,
              float* __restrict__ out,
              _Float16* __restrict__ atomh,
              _Float16* __restrict__ accum,
              unsigned* __restrict__ barA,
              unsigned* __restrict__ barB)
{
  __shared__ __attribute__((aligned(16))) char wl[17 * 16 * WSTRIDE];

  const int tid  = threadIdx.x;
  const int lane = tid & 63;
  const int wid  = blockIdx.x * 4 + (tid >> 6);
  const int q    = lane >> 4;
  const int el   = lane & 15;
  const int j0   = q * 8;
  const int gid  = blockIdx.x * 256 + tid;

  // LDS: h1 half of W (cols 16..31) + bias row, f16. (independent of ws)
  for (int i4 = tid; i4 < 17 * 16 * 32 / 4; i4 += 256) {
    const int i   = i4 * 4;
    const int s   = i >> 9;
    const int r   = i & 511;
    const int n16 = r >> 5;
    const int j   = r & 31;
    const float* src = (s < 16) ? (Kmat + s * 1024 + (n16 + 16) * 32 + j)
                                : (bias + (n16 + 16) * 32 + j);
    float4 v = *(const float4*)src;
    half4t hh = { (_Float16)v.x, (_Float16)v.y, (_Float16)v.z, (_Float16)v.w };
    *(half4t*)(wl + (s * 16 + n16) * WSTRIDE + j * 2) = hh;
  }

  // h0 W-half (cols 0..15) register-resident (proven Wr layout, h=0).
  half8 Wr[17];
  #pragma unroll
  for (int s = 0; s < 17; ++s) {
    const float* src = (s < 16) ? (Kmat + s * 1024 + el * 32 + j0)
                                : (bias + el * 32 + j0);
    half8 w;
    #pragma unroll
    for (int j = 0; j < 8; ++j) w[j] = (_Float16)src[j];
    Wr[s] = w;
  }

  // ---- Phase A: zero f16 accum + convert atom f32->f16 (grid-stride). ----
  {
    half4t* acc4 = (half4t*)accum;
    half4t* atomh4 = (half4t*)atomh;
    const float4* atom4 = (const float4*)atom;
    for (int i = gid; i < PHASEA_TOT; i += NTHR) {
      if (i < NZ4) {
        half4t z = { (_Float16)0.f, (_Float16)0.f, (_Float16)0.f, (_Float16)0.f };
        acc4[i] = z;
      } else {
        const int k = i - NZ4;
        float4 v = atom4[k];
        half4t hh = { (_Float16)v.x, (_Float16)v.y, (_Float16)v.z, (_Float16)v.w };
        atomh4[k] = hh;
      }
    }
  }
  grid_barrier(barA, MAGIC_A);   // also covers the LDS fill (__syncthreads)

  // ---- Phase B: MFMA + one-pk-instruction-per-row scatter (R6 structure,
  //      bond streamed as f32 and converted at the splat). ----
  {
    const int2* pairs2 = (const int2*)pairs;
    const char* wb = wl + el * WSTRIDE + q * 16;   // h1 frag base (n = el+16)

    auto ldpv = [&](int g) -> int2 {
      const int gc = g < GRP ? g : GRP - 1;        // clamp: loads stay valid
      int2 v = make_int2(0, 0);
      if (lane < 16) v = pairs2[gc * 16 + lane];
      return v;
    };

    int2 pv0 = ldpv(wid);
    int2 pv1 = ldpv(wid + NWAVE);

    half8 nb_c; float4v c0_c, c1_c, c2_c, c3_c;
    {
      const int a = __shfl(pv0.y, el);
      nb_c = *(const half8*)(atomh + (size_t)a * 32 + j0);
      const float4v* br = (const float4v*)(bondf + (size_t)(wid * 16 + el) * 16);
      c0_c = br[0]; c1_c = br[1]; c2_c = br[2]; c3_c = br[3];
    }

    for (int g = wid; g < GRP; g += NWAVE) {
      const int gn = g + NWAVE;

      // Stage next group (loads in flight across this group's compute).
      half8 nb_n; float4v c0_n, c1_n, c2_n, c3_n;
      {
        const int a = __shfl(pv1.y, el);
        nb_n = *(const half8*)(atomh + (size_t)a * 32 + j0);
        const int gc = gn < GRP ? gn : GRP - 1;
        const float4v* br = (const float4v*)(bondf + (size_t)(gc * 16 + el) * 16);
        c0_n = br[0]; c1_n = br[1]; c2_n = br[2]; c3_n = br[3];
      }
      const int2 pv2 = ldpv(gn + NWAVE);

      // Opaque zero (SGPR) so loop-invariant LDS reads are not hoisted.
      int zz;
      asm volatile("s_mov_b32 %0, 0" : "=s"(zz));
      const char* wbz = wb + zz;

      float4v a0 = {0.f, 0.f, 0.f, 0.f};
      float4v a1 = {0.f, 0.f, 0.f, 0.f};
      #pragma unroll
      for (int s = 0; s < 16; ++s) {
        const float scf = (s < 4) ? c0_c[s] : (s < 8) ? c1_c[s - 4]
                         : (s < 12) ? c2_c[s - 8] : c3_c[s - 12];
        const half8 af = nb_c * splat8((_Float16)scf);
        const half8 w1 = *(const half8*)(wbz + s * 16 * WSTRIDE);
        a0 = __builtin_amdgcn_mfma_f32_16x16x32_f16(af, Wr[s], a0, 0, 0, 0);
        a1 = __builtin_amdgcn_mfma_f32_16x16x32_f16(af, w1,    a1, 0, 0, 0);
      }
      {
        const half8 w1 = *(const half8*)(wbz + 16 * 16 * WSTRIDE);
        a0 = __builtin_amdgcn_mfma_f32_16x16x32_f16(nb_c, Wr[16], a0, 0, 0, 0);
        a1 = __builtin_amdgcn_mfma_f32_16x16x32_f16(nb_c, w1,     a1, 0, 0, 0);
      }

      // Epilogue: one pk-atomic instruction per 4 edge-rows (full 64B row).
      const bool ev = !(el & 1);
      #pragma unroll
      for (int r = 0; r < 4; ++r) {
        const int   d  = __shfl(pv0.x, q * 4 + r);
        const float v0 = a0[r], v1 = a1[r];
        const float p0 = __shfl_xor(v0, 1);
        const float p1 = __shfl_xor(v1, 1);
        union { _Float16 f[2]; __half2 h; } u;
        u.f[0] = ev ? (_Float16)v0 : (_Float16)p1;
        u.f[1] = ev ? (_Float16)p0 : (_Float16)v1;
        const int col = ev ? el : (15 + el);
        unsafeAtomicAdd(reinterpret_cast<__half2*>(
                            accum + (size_t)d * 32 + col), u.h);
      }

      pv0 = pv1; pv1 = pv2;
      nb_c = nb_n;
      c0_c = c0_n; c1_c = c1_n; c2_c = c2_n; c3_c = c3_n;
    }
  }
  grid_barrier(barB, MAGIC_B);

  // ---- Phase C: accum f16 -> out f32. Agent-scope atomic loads: bypass the
  // stale clean L2 lines left by phase-A zeroing (phase-B RMWs hit fabric).
  {
    const unsigned long long* acc8 = (const unsigned long long*)accum;
    float4* out4 = (float4*)out;
    for (int i = gid; i < NZ4; i += NTHR) {
      unsigned long long bits = __hip_atomic_load(acc8 + i, __ATOMIC_RELAXED,
                                                  __HIP_MEMORY_SCOPE_AGENT);
      union { unsigned long long u; half4t h; } cv;
      cv.u = bits;
      out4[i] = make_float4((float)cv.h[0], (float)cv.h[1],
                            (float)cv.h[2], (float)cv.h[3]);
    }
  }
}

extern "C" void kernel_launch(void* const* d_in, const int* in_sizes, int n_in,
                              void* d_out, int out_size, void* d_ws, size_t ws_size,
                              hipStream_t stream) {
  const float* atom  = (const float*)d_in[0];   // (100000, 32) f32
  const float* bondf = (const float*)d_in[1];   // (400000, 16) f32
  const int*   pairs = (const int*)d_in[2];     // (400000, 2) int32
  const float* Kmat  = (const float*)d_in[3];   // (16, 1024) f32
  const float* bias  = (const float*)d_in[4];   // (1024,) f32
  float* out = (float*)d_out;                   // (100000, 32) f32

  char* ws = (char*)d_ws;
  _Float16* atomh = (_Float16*)(ws + OFF_ATOMH);
  _Float16* accum = (_Float16*)(ws + OFF_ACC);
  unsigned* barA  = (unsigned*)(ws + OFF_BARA);
  unsigned* barB  = (unsigned*)(ws + OFF_BARB);

  edge_all<<<NBLK, 256, 0, stream>>>(atom, bondf, pairs, Kmat, bias, out,
                                     atomh, accum, barA, barB);
}

// Round 9
// 319.344 us; speedup vs baseline: 1.0669x; 1.0669x over previous
//
#include <hip/hip_runtime.h>
#include <hip/hip_fp16.h>

// EdgeNetwork: SINGLE persistent kernel (prep -> barrier -> MFMA+pk-atomic
// scatter -> barrier -> finalize).
//
// Journal:
// R0: hipLaunchCooperativeKernel silently no-ops under graph capture. NEVER.
// R1: occupancy x2 -> neutral. Not latency-bound.
// R3: dst-sort cut touches 3x but +3 dispatches (~8-10us each) -> net loss.
// R4: launch_bounds(256,4) -> VGPR 80->64 scratch spills. Keep (256,3).
// R5: pk_add_f16 halved atomic DWORDS, time unchanged -> wall = atomic
//     SECTOR-TOUCHES at the coherence point (~14.5G touches/s).
// R6: full-row waves, 1 pk-instr per edge-row: 800k->400k touches, edge <42us.
//     Harness re-poisons the FULL 256MB ws every iteration (43us, fixed).
// R7: __hip_atomic_fence doesn't exist -> __builtin_amdgcn_fence(ord,"agent").
// R8: megakernel CORRECT but 285us: all-thread fetch_add(0) spin = 590k fabric
//     RMWs/round on 48 lines (~40us/round!) + contends with phase-B atomics.
//     A self-inflicted atomic-pipe DoS. Lesson: spin with LOADS, and from as
//     few threads as possible.
// R9 (this): leader barrier. Arrive = 1 magic-exchange per block (poison-safe,
//     proven). Block 0 wave 0 polls all 768 flags with atomic LOADS (64x12),
//     releases one `go` dword; all others poll that single dword (1 load /
//     ~0.4us sleep). ~400x less spin traffic, atomic pipe left to phase B.
//     Agent-scope relaxed atomic loads validated by R8's correct phase C.

typedef _Float16 half8 __attribute__((ext_vector_type(8)));
typedef _Float16 half4t __attribute__((ext_vector_type(4)));
typedef float float4v __attribute__((ext_vector_type(4)));

constexpr int NA = 100000;
constexpr int E  = 400000;
constexpr int GRP   = E / 16;          // 25000 16-edge groups
constexpr int NBLK  = 768;             // exactly co-resident (3 blk/CU proof:
                                       // launch_bounds(256,3) caps VGPR<=170,
                                       // LDS 21.8KB -> 7/CU; 768 = 256CU x 3)
constexpr int NWAVE = NBLK * 4;        // 3072 persistent waves
constexpr int NTHR  = NBLK * 256;      // 196608 threads

// ---- workspace layout (bytes) ----
constexpr size_t OFF_ATOMH = 0;                    // f16[NA*32]  6.4 MB
constexpr size_t OFF_ACC   = (size_t)NA * 32 * 2;  // f16[NA*32]  6.4 MB
constexpr size_t OFF_BARA  = OFF_ACC + (size_t)NA * 32 * 2;   // u32[768]
constexpr size_t OFF_BARB  = OFF_BARA + 4096;                 // u32[768]
constexpr size_t OFF_GO    = OFF_BARB + 4096;                 // u32[2]

constexpr unsigned MAGIC_A = 0x9E3779B1u;   // not byte-replicated (poison-safe)
constexpr unsigned MAGIC_B = 0x85EBCA77u;

constexpr int NZ4 = NA * 32 / 4;       // accum zero, half4t units (800k)
constexpr int NA4 = NA * 32 / 4;       // atom convert, float4 units (800k)
constexpr int PHASEA_TOT = NZ4 + NA4;  // 1.6M

constexpr int WSTRIDE = 80;            // LDS bytes per W n-row

static __device__ inline half8 splat8(_Float16 v) {
  half8 r = {v, v, v, v, v, v, v, v};
  return r;
}

// Device-wide barrier over exactly-resident NBLK blocks. Leader polls flags
// with LOADS; everyone else polls one `go` dword. No RMW spin (R8 lesson).
static __device__ inline void grid_barrier(unsigned* flags, unsigned* go,
                                           unsigned magic) {
  __threadfence();            // release: drain stores+atomics to fabric
  __syncthreads();
  if (threadIdx.x == 0) {
    (void)__hip_atomic_exchange(flags + blockIdx.x, magic, __ATOMIC_RELEASE,
                                __HIP_MEMORY_SCOPE_AGENT);
  }
  if (blockIdx.x == 0) {
    if (threadIdx.x < 64) {                      // leader wave polls 768 flags
      for (;;) {
        int ok = 1;
        #pragma unroll
        for (int r = 0; r < 12; ++r) {           // 64*12 = 768
          unsigned v = __hip_atomic_load(flags + threadIdx.x + r * 64,
                                         __ATOMIC_RELAXED,
                                         __HIP_MEMORY_SCOPE_AGENT);
          ok &= (v == magic);
        }
        if (__all(ok)) break;
        __builtin_amdgcn_s_sleep(16);
      }
      if (threadIdx.x == 0)
        (void)__hip_atomic_exchange(go, magic, __ATOMIC_RELEASE,
                                    __HIP_MEMORY_SCOPE_AGENT);
    }
  } else {
    if (threadIdx.x == 0) {
      while (__hip_atomic_load(go, __ATOMIC_RELAXED,
                               __HIP_MEMORY_SCOPE_AGENT) != magic)
        __builtin_amdgcn_s_sleep(16);
    }
  }
  __syncthreads();
  __builtin_amdgcn_fence(__ATOMIC_ACQUIRE, "agent");
}

__global__ __launch_bounds__(256, 3)
void edge_all(const float* __restrict__ atom,
              const float* __restrict__ bondf,
              const int* __restrict__ pairs,
              const float* __restrict__ Kmat,
              const float* __restrict__ bias,
              float* __restrict__ out,
              _Float16* __restrict__ atomh,
              _Float16* __restrict__ accum,
              unsigned* __restrict__ barA,
              unsigned* __restrict__ barB,
              unsigned* __restrict__ go)
{
  __shared__ __attribute__((aligned(16))) char wl[17 * 16 * WSTRIDE];

  const int tid  = threadIdx.x;
  const int lane = tid & 63;
  const int wid  = blockIdx.x * 4 + (tid >> 6);
  const int q    = lane >> 4;
  const int el   = lane & 15;
  const int j0   = q * 8;
  const int gid  = blockIdx.x * 256 + tid;

  // LDS: h1 half of W (cols 16..31) + bias row, f16. (independent of ws)
  for (int i4 = tid; i4 < 17 * 16 * 32 / 4; i4 += 256) {
    const int i   = i4 * 4;
    const int s   = i >> 9;
    const int r   = i & 511;
    const int n16 = r >> 5;
    const int j   = r & 31;
    const float* src = (s < 16) ? (Kmat + s * 1024 + (n16 + 16) * 32 + j)
                                : (bias + (n16 + 16) * 32 + j);
    float4 v = *(const float4*)src;
    half4t hh = { (_Float16)v.x, (_Float16)v.y, (_Float16)v.z, (_Float16)v.w };
    *(half4t*)(wl + (s * 16 + n16) * WSTRIDE + j * 2) = hh;
  }

  // h0 W-half (cols 0..15) register-resident (proven Wr layout, h=0).
  half8 Wr[17];
  #pragma unroll
  for (int s = 0; s < 17; ++s) {
    const float* src = (s < 16) ? (Kmat + s * 1024 + el * 32 + j0)
                                : (bias + el * 32 + j0);
    half8 w;
    #pragma unroll
    for (int j = 0; j < 8; ++j) w[j] = (_Float16)src[j];
    Wr[s] = w;
  }

  // ---- Phase A: zero f16 accum + convert atom f32->f16 (grid-stride). ----
  {
    half4t* acc4 = (half4t*)accum;
    half4t* atomh4 = (half4t*)atomh;
    const float4* atom4 = (const float4*)atom;
    for (int i = gid; i < PHASEA_TOT; i += NTHR) {
      if (i < NZ4) {
        half4t z = { (_Float16)0.f, (_Float16)0.f, (_Float16)0.f, (_Float16)0.f };
        acc4[i] = z;
      } else {
        const int k = i - NZ4;
        float4 v = atom4[k];
        half4t hh = { (_Float16)v.x, (_Float16)v.y, (_Float16)v.z, (_Float16)v.w };
        atomh4[k] = hh;
      }
    }
  }
  grid_barrier(barA, go + 0, MAGIC_A);   // also covers LDS fill (__syncthreads)

  // ---- Phase B: MFMA + one-pk-instruction-per-row scatter (R6 structure,
  //      bond streamed as f32 and converted at the splat). ----
  {
    const int2* pairs2 = (const int2*)pairs;
    const char* wb = wl + el * WSTRIDE + q * 16;   // h1 frag base (n = el+16)

    auto ldpv = [&](int g) -> int2 {
      const int gc = g < GRP ? g : GRP - 1;        // clamp: loads stay valid
      int2 v = make_int2(0, 0);
      if (lane < 16) v = pairs2[gc * 16 + lane];
      return v;
    };

    int2 pv0 = ldpv(wid);
    int2 pv1 = ldpv(wid + NWAVE);

    half8 nb_c; float4v c0_c, c1_c, c2_c, c3_c;
    {
      const int a = __shfl(pv0.y, el);
      nb_c = *(const half8*)(atomh + (size_t)a * 32 + j0);
      const float4v* br = (const float4v*)(bondf + (size_t)(wid * 16 + el) * 16);
      c0_c = br[0]; c1_c = br[1]; c2_c = br[2]; c3_c = br[3];
    }

    for (int g = wid; g < GRP; g += NWAVE) {
      const int gn = g + NWAVE;

      // Stage next group (loads in flight across this group's compute).
      half8 nb_n; float4v c0_n, c1_n, c2_n, c3_n;
      {
        const int a = __shfl(pv1.y, el);
        nb_n = *(const half8*)(atomh + (size_t)a * 32 + j0);
        const int gc = gn < GRP ? gn : GRP - 1;
        const float4v* br = (const float4v*)(bondf + (size_t)(gc * 16 + el) * 16);
        c0_n = br[0]; c1_n = br[1]; c2_n = br[2]; c3_n = br[3];
      }
      const int2 pv2 = ldpv(gn + NWAVE);

      // Opaque zero (SGPR) so loop-invariant LDS reads are not hoisted.
      int zz;
      asm volatile("s_mov_b32 %0, 0" : "=s"(zz));
      const char* wbz = wb + zz;

      float4v a0 = {0.f, 0.f, 0.f, 0.f};
      float4v a1 = {0.f, 0.f, 0.f, 0.f};
      #pragma unroll
      for (int s = 0; s < 16; ++s) {
        const float scf = (s < 4) ? c0_c[s] : (s < 8) ? c1_c[s - 4]
                         : (s < 12) ? c2_c[s - 8] : c3_c[s - 12];
        const half8 af = nb_c * splat8((_Float16)scf);
        const half8 w1 = *(const half8*)(wbz + s * 16 * WSTRIDE);
        a0 = __builtin_amdgcn_mfma_f32_16x16x32_f16(af, Wr[s], a0, 0, 0, 0);
        a1 = __builtin_amdgcn_mfma_f32_16x16x32_f16(af, w1,    a1, 0, 0, 0);
      }
      {
        const half8 w1 = *(const half8*)(wbz + 16 * 16 * WSTRIDE);
        a0 = __builtin_amdgcn_mfma_f32_16x16x32_f16(nb_c, Wr[16], a0, 0, 0, 0);
        a1 = __builtin_amdgcn_mfma_f32_16x16x32_f16(nb_c, w1,     a1, 0, 0, 0);
      }

      // Epilogue: one pk-atomic instruction per 4 edge-rows (full 64B row).
      const bool ev = !(el & 1);
      #pragma unroll
      for (int r = 0; r < 4; ++r) {
        const int   d  = __shfl(pv0.x, q * 4 + r);
        const float v0 = a0[r], v1 = a1[r];
        const float p0 = __shfl_xor(v0, 1);
        const float p1 = __shfl_xor(v1, 1);
        union { _Float16 f[2]; __half2 h; } u;
        u.f[0] = ev ? (_Float16)v0 : (_Float16)p1;
        u.f[1] = ev ? (_Float16)p0 : (_Float16)v1;
        const int col = ev ? el : (15 + el);
        unsafeAtomicAdd(reinterpret_cast<__half2*>(
                            accum + (size_t)d * 32 + col), u.h);
      }

      pv0 = pv1; pv1 = pv2;
      nb_c = nb_n;
      c0_c = c0_n; c1_c = c1_n; c2_c = c2_n; c3_c = c3_n;
    }
  }
  grid_barrier(barB, go + 1, MAGIC_B);

  // ---- Phase C: accum f16 -> out f32. Agent-scope atomic loads: bypass the
  // stale clean L2 lines left by phase-A zeroing (phase-B RMWs hit fabric).
  {
    const unsigned long long* acc8 = (const unsigned long long*)accum;
    float4* out4 = (float4*)out;
    for (int i = gid; i < NZ4; i += NTHR) {
      unsigned long long bits = __hip_atomic_load(acc8 + i, __ATOMIC_RELAXED,
                                                  __HIP_MEMORY_SCOPE_AGENT);
      union { unsigned long long u; half4t h; } cv;
      cv.u = bits;
      out4[i] = make_float4((float)cv.h[0], (float)cv.h[1],
                            (float)cv.h[2], (float)cv.h[3]);
    }
  }
}

extern "C" void kernel_launch(void* const* d_in, const int* in_sizes, int n_in,
                              void* d_out, int out_size, void* d_ws, size_t ws_size,
                              hipStream_t stream) {
  const float* atom  = (const float*)d_in[0];   // (100000, 32) f32
  const float* bondf = (const float*)d_in[1];   // (400000, 16) f32
  const int*   pairs = (const int*)d_in[2];     // (400000, 2) int32
  const float* Kmat  = (const float*)d_in[3];   // (16, 1024) f32
  const float* bias  = (const float*)d_in[4];   // (1024,) f32
  float* out = (float*)d_out;                   // (100000, 32) f32

  char* ws = (char*)d_ws;
  _Float16* atomh = (_Float16*)(ws + OFF_ATOMH);
  _Float16* accum = (_Float16*)(ws + OFF_ACC);
  unsigned* barA  = (unsigned*)(ws + OFF_BARA);
  unsigned* barB  = (unsigned*)(ws + OFF_BARB);
  unsigned* go    = (unsigned*)(ws + OFF_GO);

  edge_all<<<NBLK, 256, 0, stream>>>(atom, bondf, pairs, Kmat, bias, out,
                                     atomh, accum, barA, barB, go);
}

// Round 10
// 124.082 us; speedup vs baseline: 2.7458x; 2.5737x over previous
//
#include <hip/hip_runtime.h>
#include <hip/hip_fp16.h>

// EdgeNetwork: 3 dispatches (PROVEN R6 structure), minimal prep.
//   k_prep: zero f16 accum + convert atom f32->f16 (bond conversion DROPPED).
//   edge_fused: full-row waves, MFMA (h0 W-half in regs, h1 in LDS), bond
//     streamed f32 + converted at the splat; epilogue = one pk-f16 atomic
//     instruction covering each edge's entire 64B accum row (400k touches).
//   k_fin: accum f16 -> out f32.
//
// Journal:
// R0: hipLaunchCooperativeKernel silently no-ops under graph capture. NEVER.
// R1: occupancy x2 -> neutral. Not latency-bound.
// R3: dst-sort cut touches 3x but +3 dispatches (~8-10us each) -> net loss.
// R4: launch_bounds(256,4) -> VGPR 80->64 scratch spills. Keep (256,3).
// R5: pk_add_f16 halved atomic DWORDS, time unchanged -> wall = atomic
//     SECTOR-TOUCHES at the coherence point (~14.5G/s). 400k = ~28us floor.
// R6: full-row waves, 1 pk-instr per edge-row: 800k->400k touches. 128.2us.
//     Harness re-poisons the FULL 256MB ws every iteration (43us, fixed).
// R7: no __hip_atomic_fence -> __builtin_amdgcn_fence(ord,"agent").
// R8: megakernel correct but 285us; blamed all-thread RMW spin.
// R9: leader/load-only barrier (400x less spin traffic) -> 260us. Theory
//     FALSIFIED: megakernel slowness is structural, not spin traffic.
//     Decision rule honored: megakernel path ABANDONED. (Validated en route:
//     magic-flag barrier, agent-scope atomic loads, bond-f32 phase B.)
// R10 (this): R6 + drop bond pre-conversion (38.4MB prep traffic to save
//     12.8MB streamed reads in an ATOMIC-bound kernel). Prep 64->25.6MB.

typedef _Float16 half8 __attribute__((ext_vector_type(8)));
typedef _Float16 half4t __attribute__((ext_vector_type(4)));
typedef float float4v __attribute__((ext_vector_type(4)));

constexpr int NA = 100000;
constexpr int E  = 400000;
constexpr int GRP   = E / 16;          // 25000 16-edge groups
constexpr int NBLK  = 768;             // 3 blocks/CU (proven spill-free)
constexpr int NWAVE = NBLK * 4;        // 3072 persistent waves

// ---- workspace layout (bytes) ----
constexpr size_t OFF_ATOMH = 0;                    // f16[NA*32]  6.4 MB
constexpr size_t OFF_ACC   = (size_t)NA * 32 * 2;  // f16[NA*32]  6.4 MB

constexpr int NZ4 = NA * 32 / 4;       // accum zero, half4t units (800k)
constexpr int NA4 = NA * 32 / 4;       // atom convert, float4 units (800k)
constexpr int PREP_TOT = NZ4 + NA4;    // 1.6M

constexpr int WSTRIDE = 80;            // LDS bytes per W n-row

// ---- k_prep: zero f16 accum + convert atom to f16 (NO bond pass) ----
__global__ void k_prep(const float* __restrict__ atom,
                       half4t* __restrict__ accz,
                       half4t* __restrict__ atomh4) {
  int i = blockIdx.x * 256 + threadIdx.x;
  if (i < NZ4) {
    half4t z = { (_Float16)0.f, (_Float16)0.f, (_Float16)0.f, (_Float16)0.f };
    accz[i] = z;
  } else if (i < PREP_TOT) {
    int k = i - NZ4;
    float4 v = ((const float4*)atom)[k];
    half4t hh = { (_Float16)v.x, (_Float16)v.y, (_Float16)v.z, (_Float16)v.w };
    atomh4[k] = hh;
  }
}

static __device__ inline half8 splat8(_Float16 v) {
  half8 r = {v, v, v, v, v, v, v, v};
  return r;
}

// ---- edge_fused: full-row MFMA + one-pk-instruction-per-row scatter ----
__global__ __launch_bounds__(256, 3)
void edge_fused(const _Float16* __restrict__ atomh,
                const float* __restrict__ bondf,
                const int* __restrict__ pairs,
                const float* __restrict__ Kmat,
                const float* __restrict__ bias,
                _Float16* __restrict__ accum)
{
  __shared__ __attribute__((aligned(16))) char wl[17 * 16 * WSTRIDE];

  const int tid  = threadIdx.x;
  const int lane = tid & 63;
  const int wid  = blockIdx.x * 4 + (tid >> 6);
  const int q    = lane >> 4;
  const int el   = lane & 15;
  const int j0   = q * 8;

  // LDS: h1 half of W (cols 16..31) + bias row, f16.
  for (int i4 = tid; i4 < 17 * 16 * 32 / 4; i4 += 256) {
    const int i   = i4 * 4;
    const int s   = i >> 9;
    const int r   = i & 511;
    const int n16 = r >> 5;
    const int j   = r & 31;
    const float* src = (s < 16) ? (Kmat + s * 1024 + (n16 + 16) * 32 + j)
                                : (bias + (n16 + 16) * 32 + j);
    float4 v = *(const float4*)src;
    half4t hh = { (_Float16)v.x, (_Float16)v.y, (_Float16)v.z, (_Float16)v.w };
    *(half4t*)(wl + (s * 16 + n16) * WSTRIDE + j * 2) = hh;
  }

  // h0 W-half (cols 0..15) register-resident (proven Wr layout).
  half8 Wr[17];
  #pragma unroll
  for (int s = 0; s < 17; ++s) {
    const float* src = (s < 16) ? (Kmat + s * 1024 + el * 32 + j0)
                                : (bias + el * 32 + j0);
    half8 w;
    #pragma unroll
    for (int j = 0; j < 8; ++j) w[j] = (_Float16)src[j];
    Wr[s] = w;
  }

  __syncthreads();

  const int2* pairs2 = (const int2*)pairs;
  const char* wb = wl + el * WSTRIDE + q * 16;   // h1 frag base (n = el+16)

  auto ldpv = [&](int g) -> int2 {
    const int gc = g < GRP ? g : GRP - 1;        // clamp: loads stay valid
    int2 v = make_int2(0, 0);
    if (lane < 16) v = pairs2[gc * 16 + lane];
    return v;
  };

  // ---- Pipeline prologue.
  int2 pv0 = ldpv(wid);
  int2 pv1 = ldpv(wid + NWAVE);

  half8 nb_c; float4v c0_c, c1_c, c2_c, c3_c;
  {
    const int a = __shfl(pv0.y, el);
    nb_c = *(const half8*)(atomh + (size_t)a * 32 + j0);
    const float4v* br = (const float4v*)(bondf + (size_t)(wid * 16 + el) * 16);
    c0_c = br[0]; c1_c = br[1]; c2_c = br[2]; c3_c = br[3];
  }

  for (int g = wid; g < GRP; g += NWAVE) {
    const int gn = g + NWAVE;

    // ---- Stage next group (loads in flight across this group's compute).
    half8 nb_n; float4v c0_n, c1_n, c2_n, c3_n;
    {
      const int a = __shfl(pv1.y, el);
      nb_n = *(const half8*)(atomh + (size_t)a * 32 + j0);
      const int gc = gn < GRP ? gn : GRP - 1;
      const float4v* br = (const float4v*)(bondf + (size_t)(gc * 16 + el) * 16);
      c0_n = br[0]; c1_n = br[1]; c2_n = br[2]; c3_n = br[3];
    }
    const int2 pv2 = ldpv(gn + NWAVE);

    // Opaque zero (SGPR) so loop-invariant LDS reads are not hoisted.
    int zz;
    asm volatile("s_mov_b32 %0, 0" : "=s"(zz));
    const char* wbz = wb + zz;

    // ---- Compute: 16 edges x 32 cols.
    float4v a0 = {0.f, 0.f, 0.f, 0.f};
    float4v a1 = {0.f, 0.f, 0.f, 0.f};
    #pragma unroll
    for (int s = 0; s < 16; ++s) {
      const float scf = (s < 4) ? c0_c[s] : (s < 8) ? c1_c[s - 4]
                       : (s < 12) ? c2_c[s - 8] : c3_c[s - 12];
      const half8 af = nb_c * splat8((_Float16)scf);
      const half8 w1 = *(const half8*)(wbz + s * 16 * WSTRIDE);
      a0 = __builtin_amdgcn_mfma_f32_16x16x32_f16(af, Wr[s], a0, 0, 0, 0);
      a1 = __builtin_amdgcn_mfma_f32_16x16x32_f16(af, w1,    a1, 0, 0, 0);
    }
    {
      const half8 w1 = *(const half8*)(wbz + 16 * 16 * WSTRIDE);
      a0 = __builtin_amdgcn_mfma_f32_16x16x32_f16(nb_c, Wr[16], a0, 0, 0, 0);
      a1 = __builtin_amdgcn_mfma_f32_16x16x32_f16(nb_c, w1,     a1, 0, 0, 0);
    }

    // ---- Epilogue: one pk-atomic instruction per 4 edge-rows (full 64B row).
    const bool ev = !(el & 1);
    #pragma unroll
    for (int r = 0; r < 4; ++r) {
      const int   d  = __shfl(pv0.x, q * 4 + r);
      const float v0 = a0[r], v1 = a1[r];
      const float p0 = __shfl_xor(v0, 1);
      const float p1 = __shfl_xor(v1, 1);
      union { _Float16 f[2]; __half2 h; } u;
      u.f[0] = ev ? (_Float16)v0 : (_Float16)p1;
      u.f[1] = ev ? (_Float16)p0 : (_Float16)v1;
      const int col = ev ? el : (15 + el);
      unsafeAtomicAdd(reinterpret_cast<__half2*>(
                          accum + (size_t)d * 32 + col), u.h);
    }

    // ---- Rotate pipeline registers.
    pv0 = pv1; pv1 = pv2;
    nb_c = nb_n;
    c0_c = c0_n; c1_c = c1_n; c2_c = c2_n; c3_c = c3_n;
  }
}

// ---- k_fin: accum f16 -> out f32 (full overwrite) ----
__global__ void k_fin(const half4t* __restrict__ acc4,
                      float4* __restrict__ out4) {
  int i = blockIdx.x * 256 + threadIdx.x;
  if (i >= NZ4) return;
  half4t v = acc4[i];
  out4[i] = make_float4((float)v[0], (float)v[1], (float)v[2], (float)v[3]);
}

extern "C" void kernel_launch(void* const* d_in, const int* in_sizes, int n_in,
                              void* d_out, int out_size, void* d_ws, size_t ws_size,
                              hipStream_t stream) {
  const float* atom  = (const float*)d_in[0];   // (100000, 32) f32
  const float* bondf = (const float*)d_in[1];   // (400000, 16) f32
  const int*   pairs = (const int*)d_in[2];     // (400000, 2) int32
  const float* Kmat  = (const float*)d_in[3];   // (16, 1024) f32
  const float* bias  = (const float*)d_in[4];   // (1024,) f32
  float* out = (float*)d_out;                   // (100000, 32) f32

  char* ws = (char*)d_ws;
  _Float16* atomh = (_Float16*)(ws + OFF_ATOMH);
  _Float16* accum = (_Float16*)(ws + OFF_ACC);

  k_prep<<<(PREP_TOT + 255) / 256, 256, 0, stream>>>(
      atom, (half4t*)accum, (half4t*)atomh);
  edge_fused<<<NBLK, 256, 0, stream>>>(atomh, bondf, pairs, Kmat, bias, accum);
  k_fin<<<(NZ4 + 255) / 256, 256, 0, stream>>>((const half4t*)accum,
                                               (float4*)out);
}